// Round 17
// baseline (19681.128 us; speedup 1.0000x reference)
//
#include <hip/hip_runtime.h>
#include <math.h>

#define EPSF 1e-5f

typedef __attribute__((ext_vector_type(2))) float f2;
typedef __attribute__((ext_vector_type(4))) float f4;
typedef __attribute__((ext_vector_type(8))) _Float16 h8;

// packed fp32 FMA with x broadcast via op_sel (lo or hi half of the x pair)
#define PK_FMA_LO(ACC, W, X) \
    asm("v_pk_fma_f32 %0, %1, %2, %0 op_sel:[0,0,0] op_sel_hi:[1,0,1]" \
        : "+v"(ACC) : "v"(W), "v"(X))
#define PK_FMA_HI(ACC, W, X) \
    asm("v_pk_fma_f32 %0, %1, %2, %0 op_sel:[0,1,0] op_sel_hi:[1,1,1]" \
        : "+v"(ACC) : "v"(W), "v"(X))

// DPP helper: v += value from lane (i - N) within the 16-lane DPP row (0 if OOB)
template<int CTRL>
__device__ __forceinline__ float dpp_add(float v) {
    int s = __builtin_amdgcn_update_dpp(0, __float_as_int(v), CTRL, 0xf, 0xf, true);
    return v + __int_as_float(s);
}

// async global->LDS, 16B per lane; LDS dest = wave-uniform base + lane*16
__device__ __forceinline__ void gl_lds16(const void* g, void* l) {
    __builtin_amdgcn_global_load_lds(
        (const __attribute__((address_space(1))) void*)g,
        (__attribute__((address_space(3))) void*)l, 16, 0, 0);
}

// ---------------- prep: weight transposes + bool-dtype detect ----------------
__global__ __launch_bounds__(256) void k_prep(
    const float* __restrict__ Wih, const float* __restrict__ Whh,
    const float* __restrict__ W2, const float* __restrict__ W3,
    const unsigned char* __restrict__ fmask,
    _Float16* __restrict__ WhhH, float* __restrict__ WxT,
    float* __restrict__ W2T, float* __restrict__ W3T, int* __restrict__ flag)
{
    int idx = blockIdx.x * 256 + threadIdx.x;
    if (idx < 196608) {                 // Whh[768][256] -> WhhH[k/8][j][8] fp16
        int j = idx >> 8, k = idx & 255;
        WhhH[(k >> 3) * 6144 + j * 8 + (k & 7)] = (_Float16)Whh[idx];
    }
    if (idx < 105984) {                 // Wih[768][138] x-part -> WxT[128][768]
        int j = idx / 138, k = idx % 138;
        if (k < 128) WxT[k * 768 + j] = Wih[idx];
    }
    if (idx < 409600) {                 // W[co][ci][5][5] -> WT[tap][ci][co]
        int co = idx / 3200, r = idx % 3200;
        int ci = r / 25, tap = r % 25;
        int dst = (tap * 128 + ci) * 128 + co;
        W2T[dst] = W2[idx];
        W3T[dst] = W3[idx];
    }
    if (idx == 0) {                     // bool stored as int32? bytes 1,2,3 of each word all zero
        int nz = 0;
        for (int i = 0; i < 4096; i++) if ((i & 3) != 0) nz |= fmask[i];
        *flag = nz ? 0 : 1;
    }
}

// ---------------- conv1: [32,1,1024,40] -> X1[b][t][m1(8)][co(128)] ----------------
__global__ __launch_bounds__(256) void k_conv1(
    const float* __restrict__ X, const float* __restrict__ W1,
    const float* __restrict__ bb, const float* __restrict__ gg,
    const float* __restrict__ be, const float* __restrict__ mm_,
    const float* __restrict__ vv, float* __restrict__ X1)
{
    __shared__ __align__(16) float xs[8][44];
    __shared__ __align__(16) float ws[25][128];
    __shared__ float sc[128], sh[128];
    int bid = blockIdx.x;
    int b = bid >> 8, t0 = (bid & 255) << 2;
    int tid = threadIdx.x;
    for (int e = tid; e < 8 * 44; e += 256) {
        int tt = e / 44, mm = e % 44;
        int gt = t0 + tt - 2, gm = mm - 2;
        float val = 0.f;
        if (gt >= 0 && gt < 1024 && gm >= 0 && gm < 40)
            val = X[(b * 1024 + gt) * 40 + gm];
        xs[tt][mm] = val;
    }
    for (int e = tid; e < 3200; e += 256) {
        int tap = e >> 7, co = e & 127;
        ws[tap][co] = W1[co * 25 + tap];
    }
    if (tid < 128) {
        float s = gg[tid] / sqrtf(vv[tid] + EPSF);
        sc[tid] = s;
        sh[tid] = (bb[tid] - mm_[tid]) * s + be[tid];
    }
    __syncthreads();
    int cog = tid >> 5;          // 8 groups x 16 co
    int m1i = (tid >> 2) & 7;    // pooled mel
    int tp  = tid & 3;           // t'
    int co0 = cog * 16;
    float val[5][16];
#pragma unroll
    for (int p = 0; p < 5; p++)
#pragma unroll
        for (int i = 0; i < 16; i++) val[p][i] = 0.f;
#pragma unroll
    for (int dt = 0; dt < 5; dt++) {
#pragma unroll
        for (int dm = 0; dm < 5; dm++) {
            float w[16];
#pragma unroll
            for (int i = 0; i < 16; i += 4)
                *(float4*)&w[i] = *(const float4*)&ws[dt * 5 + dm][co0 + i];
#pragma unroll
            for (int p = 0; p < 5; p++) {
                float x = xs[tp + dt][m1i * 5 + p + dm];
#pragma unroll
                for (int i = 0; i < 16; i++) val[p][i] = fmaf(x, w[i], val[p][i]);
            }
        }
    }
    float outv[16];
#pragma unroll
    for (int i = 0; i < 16; i++) {
        float s = sc[co0 + i], h = sh[co0 + i];
        float mx = 0.f;
#pragma unroll
        for (int p = 0; p < 5; p++) {
            float y = fmaf(val[p][i], s, h);
            y = fmaxf(y, 0.f);
            mx = fmaxf(mx, y);
        }
        outv[i] = mx;
    }
    float* dst = &X1[(((long)(b * 1024 + t0 + tp)) * 8 + m1i) * 128 + co0];
#pragma unroll
    for (int i = 0; i < 16; i += 4) *(float4*)&dst[i] = *(float4*)&outv[i];
}

// -------- conv2 v4: pk_fma + 2 t-rows/thread (w-reads amortized 2x) --------
__global__ __attribute__((amdgpu_waves_per_eu(2, 2))) __launch_bounds__(256) void k_conv2(
    const float* __restrict__ X1, const float* __restrict__ W2T,
    const float* __restrict__ bb, const float* __restrict__ gg,
    const float* __restrict__ be, const float* __restrict__ mm_,
    const float* __restrict__ vv, float* __restrict__ X2)
{
    __shared__ __align__(16) float xs[36 * 196];     // [tt][ci*12 + m]
    __shared__ __align__(16) float ws[5 * 16 * 132]; // [dm][ci][co(128, pad 132)]
    __shared__ float sc[128], sh[128];
    int bid = blockIdx.x;
    int t0 = (bid & 31) << 5, b = bid >> 5;
    int tid = threadIdx.x;
    int tp = tid & 15, cog = tid >> 4;
    if (tid < 128) {
        float s = gg[tid] / sqrtf(vv[tid] + EPSF);
        sc[tid] = s;
        sh[tid] = (bb[tid] - mm_[tid]) * s + be[tid];
    }
    f2 accp[2][4][8];                    // [t-half][co pair][m]
#pragma unroll
    for (int th = 0; th < 2; th++)
#pragma unroll
        for (int p = 0; p < 4; p++)
#pragma unroll
            for (int m = 0; m < 8; m++) accp[th][p][m] = (f2){0.f, 0.f};

    for (int cc = 0; cc < 8; cc++) {
        __syncthreads();
        for (int e = tid; e < 1728; e += 256) {
            int ci = e & 15, r = e >> 4;          // r 0..107
            int tt = r / 3, mg = r - tt * 3;
            int gt = t0 + tt - 2;
            float4 v = {0.f, 0.f, 0.f, 0.f};
            if (gt >= 0 && gt < 1024) {
                const float* src = &X1[(((long)(b * 1024 + gt)) * 8) * 128 + cc * 16 + ci];
                float* pv = (float*)&v;
#pragma unroll
                for (int k2 = 0; k2 < 4; k2++) {
                    int gm = mg * 4 + k2 - 2;
                    if (gm >= 0 && gm < 8) pv[k2] = src[gm * 128];
                }
            }
            *(float4*)&xs[tt * 196 + ci * 12 + mg * 4] = v;
        }
        for (int dt = 0; dt < 5; dt++) {
            __syncthreads();
            for (int e = tid; e < 10240; e += 256) {
                int co = e & 127, ci = (e >> 7) & 15, dm = e >> 11;
                ws[dm * 2112 + ci * 132 + co] =
                    W2T[((dt * 5 + dm) * 128 + cc * 16 + ci) * 128 + co];
            }
            __syncthreads();
            for (int ci = 0; ci < 16; ci++) {
                f2 x2[2][6];
#pragma unroll
                for (int th = 0; th < 2; th++) {
                    const float* xp = &xs[(tp + th * 16 + dt) * 196 + ci * 12];
                    f4 a = *(const f4*)&xp[0];
                    f4 bv = *(const f4*)&xp[4];
                    f4 cv = *(const f4*)&xp[8];
                    x2[th][0] = (f2){a.x, a.y};   x2[th][1] = (f2){a.z, a.w};
                    x2[th][2] = (f2){bv.x, bv.y}; x2[th][3] = (f2){bv.z, bv.w};
                    x2[th][4] = (f2){cv.x, cv.y}; x2[th][5] = (f2){cv.z, cv.w};
                }
                const float* wb = &ws[ci * 132];
#pragma unroll
                for (int dm = 0; dm < 5; dm++) {
                    const float* wr = wb + dm * 2112;
                    f4 wa = *(const f4*)&wr[cog * 4];
                    f4 wbv = *(const f4*)&wr[64 + cog * 4];
                    f2 wp[4];
                    wp[0] = (f2){wa.x, wa.y};   wp[1] = (f2){wa.z, wa.w};
                    wp[2] = (f2){wbv.x, wbv.y}; wp[3] = (f2){wbv.z, wbv.w};
#pragma unroll
                    for (int th = 0; th < 2; th++)
#pragma unroll
                        for (int m = 0; m < 8; m++) {
                            const int j = m + dm;
                            f2 xpair = x2[th][j >> 1];
                            if (j & 1) {
                                PK_FMA_HI(accp[th][0][m], wp[0], xpair);
                                PK_FMA_HI(accp[th][1][m], wp[1], xpair);
                                PK_FMA_HI(accp[th][2][m], wp[2], xpair);
                                PK_FMA_HI(accp[th][3][m], wp[3], xpair);
                            } else {
                                PK_FMA_LO(accp[th][0][m], wp[0], xpair);
                                PK_FMA_LO(accp[th][1][m], wp[1], xpair);
                                PK_FMA_LO(accp[th][2][m], wp[2], xpair);
                                PK_FMA_LO(accp[th][3][m], wp[3], xpair);
                            }
                        }
                }
            }
        }
    }
#pragma unroll
    for (int th = 0; th < 2; th++) {
        int t = t0 + th * 16 + tp;
#pragma unroll
        for (int g = 0; g < 2; g++) {
            int cobase = g * 64 + cog * 4;
#pragma unroll
            for (int m2 = 0; m2 < 2; m2++) {
                float4 ov;
                float* po = (float*)&ov;
#pragma unroll
                for (int c = 0; c < 4; c++) {
                    float s = sc[cobase + c], h = sh[cobase + c];
                    float mx = 0.f;
#pragma unroll
                    for (int q = 0; q < 4; q++) {
                        f2 av = accp[th][g * 2 + (c >> 1)][m2 * 4 + q];
                        float a = (c & 1) ? av.y : av.x;
                        float y = fmaf(a, s, h);
                        y = fmaxf(y, 0.f);
                        mx = fmaxf(mx, y);
                    }
                    po[c] = mx;
                }
                *(float4*)&X2[(((long)(b * 1024 + t)) * 2 + m2) * 128 + cobase] = ov;
            }
        }
    }
}

// ------- conv3 (tap-pruned, conflict-free; validated R9: conflicts 6.5e8 -> 0) -------
__global__ __launch_bounds__(256) void k_conv3(
    const float* __restrict__ X2, const float* __restrict__ W3T,
    const float* __restrict__ bb, const float* __restrict__ gg,
    const float* __restrict__ be, const float* __restrict__ mm_,
    const float* __restrict__ vv, float* __restrict__ F)
{
    __shared__ __align__(16) float xs[20 * 66];     // [t''][ci*2+m], stride 66
    __shared__ __align__(16) float ws[3][32][64];   // [dm-1][ci][co]
    __shared__ float sc[64], sh[64];
    int bid = blockIdx.x;
    int coh = bid & 1, t0 = ((bid >> 1) & 63) << 4, b = bid >> 7;
    int co_base = coh * 64;
    int tid = threadIdx.x;
    int tp = tid & 15, cog = tid >> 4;
    if (tid < 64) {
        int co = co_base + tid;
        float s = gg[co] / sqrtf(vv[co] + EPSF);
        sc[tid] = s;
        sh[tid] = (bb[co] - mm_[co]) * s + be[co];
    }
    float acc[4][2];
#pragma unroll
    for (int c = 0; c < 4; c++) { acc[c][0] = 0.f; acc[c][1] = 0.f; }

    for (int cc = 0; cc < 4; cc++) {
        __syncthreads();
        for (int e = tid; e < 20 * 64; e += 256) {
            int tt = e >> 6, r = e & 63;
            int ci = r >> 1, m = r & 1;
            int gt = t0 + tt - 2;
            float v = 0.f;
            if (gt >= 0 && gt < 1024)
                v = X2[(((long)(b * 1024 + gt)) * 2 + m) * 128 + cc * 32 + ci];
            xs[tt * 66 + ci * 2 + m] = v;
        }
        for (int dt = 0; dt < 5; dt++) {
            __syncthreads();
            for (int e = tid; e < 3 * 32 * 64; e += 256) {
                int co = e & 63, ci = (e >> 6) & 31, dmi = e >> 11;
                ws[dmi][ci][co] = W3T[((dt * 5 + dmi + 1) * 128 + cc * 32 + ci) * 128 + co_base + co];
            }
            __syncthreads();
            for (int ci = 0; ci < 32; ci++) {
                float2 x = *(const float2*)&xs[(tp + dt) * 66 + ci * 2];
                float w1[4], w2[4], w3[4];
                *(float4*)w1 = *(const float4*)&ws[0][ci][cog * 4];
                *(float4*)w2 = *(const float4*)&ws[1][ci][cog * 4];
                *(float4*)w3 = *(const float4*)&ws[2][ci][cog * 4];
#pragma unroll
                for (int c = 0; c < 4; c++) acc[c][0] = fmaf(w2[c], x.x, acc[c][0]);
#pragma unroll
                for (int c = 0; c < 4; c++) acc[c][0] = fmaf(w3[c], x.y, acc[c][0]);
#pragma unroll
                for (int c = 0; c < 4; c++) acc[c][1] = fmaf(w1[c], x.x, acc[c][1]);
#pragma unroll
                for (int c = 0; c < 4; c++) acc[c][1] = fmaf(w2[c], x.y, acc[c][1]);
            }
        }
    }
    float4 ov;
    float* po = (float*)&ov;
#pragma unroll
    for (int c = 0; c < 4; c++) {
        float s = sc[cog * 4 + c], h = sh[cog * 4 + c];
        float y0 = fmaxf(fmaf(acc[c][0], s, h), 0.f);
        float y1 = fmaxf(fmaf(acc[c][1], s, h), 0.f);
        po[c] = fmaxf(y0, y1);
    }
    *(float4*)&F[((long)(t0 + tp) * 32 + b) * 128 + co_base + cog * 4] = ov;
}

// ---------------- Gx = F @ Wihx.T + bih : [32768,128]x[128,768] ----------------
__global__ __launch_bounds__(256) void k_gemm(
    const float* __restrict__ F, const float* __restrict__ WxT,
    const float* __restrict__ bih, float* __restrict__ Gx)
{
    __shared__ __align__(16) float Fs[64][33];
    __shared__ __align__(16) float Ws[32][256];
    int bid = blockIdx.x;
    int jt = bid % 3, tb0 = (bid / 3) * 64;
    int tid = threadIdx.x;
    int tx = tid & 31, ty = tid >> 5;
    float acc[8][8];
#pragma unroll
    for (int i = 0; i < 8; i++)
#pragma unroll
        for (int j = 0; j < 8; j++) acc[i][j] = 0.f;
    for (int cc = 0; cc < 4; cc++) {
        __syncthreads();
        for (int e = tid; e < 64 * 32; e += 256) {
            int ci = e & 31, i = e >> 5;
            Fs[i][ci] = F[(long)(tb0 + i) * 128 + cc * 32 + ci];
        }
        for (int e = tid; e < 32 * 256; e += 256) {
            int jj = e & 255, ci = e >> 8;
            Ws[ci][jj] = WxT[(cc * 32 + ci) * 768 + jt * 256 + jj];
        }
        __syncthreads();
        for (int ci = 0; ci < 32; ci++) {
            float a[8], w[8];
#pragma unroll
            for (int i = 0; i < 8; i++) a[i] = Fs[ty * 8 + i][ci];
            *(float4*)&w[0] = *(const float4*)&Ws[ci][tx * 8];
            *(float4*)&w[4] = *(const float4*)&Ws[ci][tx * 8 + 4];
#pragma unroll
            for (int i = 0; i < 8; i++)
#pragma unroll
                for (int j = 0; j < 8; j++) acc[i][j] = fmaf(a[i], w[j], acc[i][j]);
        }
    }
    float bj[8];
#pragma unroll
    for (int j = 0; j < 8; j++) bj[j] = bih[jt * 256 + tx * 8 + j];
#pragma unroll
    for (int i = 0; i < 8; i++) {
        float o[8];
#pragma unroll
        for (int j = 0; j < 8; j++) o[j] = acc[i][j] + bj[j];
        float* dst = &Gx[(long)(tb0 + ty * 8 + i) * 768 + jt * 256 + tx * 8];
        *(float4*)&dst[0] = *(float4*)&o[0];
        *(float4*)&dst[4] = *(float4*)&o[4];
    }
}

// ====== GRU ring v6: hybrid register-resident + DMA ring (fp16 w, fp32 h) ======
// v4 (4.87 ms) is ~97% of its LDS floor, so the lever is BYTES: consumer thread
// j pins its chunks 0-2 weights in 12 h8 = 48 VGPRs (coalesced pre-loop loads;
// 60 base + 48 = ~108 < 128 cap -- sized NOT to spill, unlike R2-R5's 96-192-reg
// asks). Per step: chunks 0-2 from registers (no DMA, no LDS w-reads), chunks
// 3-7 stream through the 3-slot ring (5 barriers vs 8). k-ascending order
// preserved => bitwise-identical to v4. Spill signature to watch: VGPR~56 +
// WRITE_SIZE in MBs => revert.
__global__ __attribute__((amdgpu_waves_per_eu(4, 4))) __launch_bounds__(1024) void k_gru(
    const _Float16* __restrict__ WhhH, const float* __restrict__ Gx,
    const float* __restrict__ Wih, const float* __restrict__ bhh_g,
    const float* __restrict__ Wf, const float* __restrict__ bf_g,
    const float* __restrict__ targets, const unsigned char* __restrict__ fmask,
    const int* __restrict__ flag, float* __restrict__ out)
{
    extern __shared__ float lds[];
    char* bufb  = (char*)lds;       // 3 slots * 49152 B = 147456 B
    float* hq   = lds + 36864;      // 256
    float* gsum = hq + 256;         // 768
    float* tfl  = gsum + 768;       // 16
    const int b = blockIdx.x, tid = threadIdx.x;
    const int lane = tid & 63, wvi = tid >> 6;
    const bool isCons = (wvi < 12);
    const bool isGate = (tid < 256);
    const bool isProj = (tid >= 256 && tid < 416);
    const bool isProd = (wvi >= 12);

    float wtf0[10], wtf1[10], wtf2[10];
    float bh0 = 0.f, bh1 = 0.f, bh2 = 0.f, hold = 0.f;
    if (isGate) {
#pragma unroll
        for (int c = 0; c < 10; c++) {
            wtf0[c] = Wih[tid * 138 + 128 + c];
            wtf1[c] = Wih[(tid + 256) * 138 + 128 + c];
            wtf2[c] = Wih[(tid + 512) * 138 + 128 + c];
        }
        bh0 = bhh_g[tid]; bh1 = bhh_g[tid + 256]; bh2 = bhh_g[tid + 512];
    }
    const int oc = (tid - 256) >> 4, seg = tid & 15;
    float wf16[16];
    float bfc = 0.f;
    int int32mode = 0;
    if (isProj) {
#pragma unroll
        for (int i = 0; i < 16; i++) wf16[i] = Wf[oc * 256 + seg * 16 + i];
        bfc = bf_g[oc];
        int32mode = flag[0];
    }
    const bool isWr = isProj && (seg == 15);

    // persistent weights: chunks 0-2 (k-groups 0..11), 12 h8 = 48 VGPRs
    const h8* WhhHv = (const h8*)WhhH;
    h8 wreg[12];
    if (isCons) {
#pragma unroll
        for (int i = 0; i < 12; i++) wreg[i] = WhhHv[i * 768 + tid];
    } else {
#pragma unroll
        for (int i = 0; i < 12; i++) wreg[i] = (h8)(_Float16)0.f;
    }

    if (tid < 256) hq[tid] = 0.f;
    if (tid < 16) tfl[tid] = 0.f;
    __syncthreads();   // no gl_lds outstanding yet: safe

    const int wv = wvi - 12;          // producer wave 0..3
    const char* WhhB = (const char*)WhhH;
    // prologue: stage streamed chunks 3 (slot0) and 4 (slot1)
    if (isProd) {
        for (int g = 0; g < 2; g++) {
#pragma unroll
            for (int i = 0; i < 12; i++) {
                int off = (wv * 12 + i) * 1024;
                gl_lds16(WhhB + (3 + g) * 49152 + off + lane * 16, bufb + g * 49152 + off);
            }
        }
        asm volatile("s_waitcnt vmcnt(12)");   // chunk 3 arrived
    }
    asm volatile("s_barrier" ::: "memory");

    const f4* fh = (const f4*)hq;
    int slotc = 0, slotp = 2;

    for (int t = 0; t < 1024; t++) {
        float gxr = 0.f, gxz = 0.f, gxn = 0.f;
        if (isGate) {
            const float* gx = &Gx[((long)t * 32 + b) * 768];
            gxr = gx[tid]; gxz = gx[tid + 256]; gxn = gx[tid + 512];
        }
        float tgt = 0.f; int fmv = 0;
        if (isWr) {
            tgt = targets[((long)b * 1024 + t) * 10 + oc];
            fmv = int32mode ? ((const int*)fmask)[t * 32 + b] : (int)fmask[t * 32 + b];
        }
        float acc = 0.f;

        // ---- chunks 0-2 from registers (no barriers, no LDS weight traffic) ----
        if (isCons) {
#pragma unroll
            for (int c = 0; c < 3; c++) {
#pragma unroll
                for (int g = 0; g < 4; g++) {
                    h8 w = wreg[c * 4 + g];
                    f4 ha = fh[c * 8 + g * 2], hb = fh[c * 8 + g * 2 + 1];
                    acc = fmaf((float)w[0], ha.x, acc);
                    acc = fmaf((float)w[1], ha.y, acc);
                    acc = fmaf((float)w[2], ha.z, acc);
                    acc = fmaf((float)w[3], ha.w, acc);
                    acc = fmaf((float)w[4], hb.x, acc);
                    acc = fmaf((float)w[5], hb.y, acc);
                    acc = fmaf((float)w[6], hb.z, acc);
                    acc = fmaf((float)w[7], hb.w, acc);
                }
            }
        }

        // ---- chunks 3-7 via ring ----
        for (int cs = 0; cs < 5; cs++) {
            if (isProd) {
                int rs = cs + 2; if (rs >= 5) rs -= 5;     // streamed chunk being staged
                const char* srcb = WhhB + (3 + rs) * 49152;
                char* dstb = bufb + slotp * 49152;
#pragma unroll
                for (int i = 0; i < 12; i++) {
                    int off = (wv * 12 + i) * 1024;
                    gl_lds16(srcb + off + lane * 16, dstb + off);
                }
                asm volatile("s_waitcnt vmcnt(12)");       // next chunk arrived
            } else if (isCons) {
                const int c = 3 + cs;
                const h8* wp = (const h8*)(bufb + slotc * 49152);
#pragma unroll
                for (int g = 0; g < 4; g++) {
                    h8 w = wp[g * 768 + tid];
                    f4 ha = fh[c * 8 + g * 2], hb = fh[c * 8 + g * 2 + 1];
                    acc = fmaf((float)w[0], ha.x, acc);
                    acc = fmaf((float)w[1], ha.y, acc);
                    acc = fmaf((float)w[2], ha.z, acc);
                    acc = fmaf((float)w[3], ha.w, acc);
                    acc = fmaf((float)w[4], hb.x, acc);
                    acc = fmaf((float)w[5], hb.y, acc);
                    acc = fmaf((float)w[6], hb.z, acc);
                    acc = fmaf((float)w[7], hb.w, acc);
                }
            }
            slotc++; if (slotc == 3) slotc = 0;
            slotp++; if (slotp == 3) slotp = 0;
            asm volatile("s_barrier" ::: "memory");
        }

        if (isCons) gsum[tid] = acc;
        asm volatile("s_barrier" ::: "memory");   // B1: gsum ready

        if (isGate) {
            float gr = gxr, gz = gxz, gn = gxn;
#pragma unroll
            for (int c = 0; c < 10; c++) {
                float tv = tfl[c];
                gr = fmaf(tv, wtf0[c], gr);
                gz = fmaf(tv, wtf1[c], gz);
                gn = fmaf(tv, wtf2[c], gn);
            }
            float ar = gsum[tid] + bh0;
            float az = gsum[tid + 256] + bh1;
            float an = gsum[tid + 512] + bh2;
            float r = 1.0f / (1.0f + expf(-(gr + ar)));
            float z = 1.0f / (1.0f + expf(-(gz + az)));
            float n = tanhf(fmaf(r, an, gn));
            float hnew = (1.0f - z) * n + z * hold;
            hold = hnew;
            hq[tid] = hnew;
        }
        asm volatile("s_barrier" ::: "memory");   // B2: h ready

        if (isProj) {
            const float* hp = &hq[seg * 16];
            float s = 0.f;
#pragma unroll
            for (int i = 0; i < 16; i++) s = fmaf(wf16[i], hp[i], s);
            s = dpp_add<0x111>(s);
            s = dpp_add<0x112>(s);
            s = dpp_add<0x114>(s);
            s = dpp_add<0x118>(s);   // lane seg==15 holds full sum
            if (isWr) {
                float o = s + bfc;
                out[((long)b * 1024 + t) * 10 + oc] = o;
                float pred = (o > 0.f) ? 1.f : 0.f;
                tfl[oc] = fmv ? tgt : pred;
            }
        }
        // no extra barrier: hq/tfl consumers separated by next step's chunk
        // barriers + B1 before first use.
    }
}

// ---------------- fallback GRU (R5): used only if dynamic LDS rejected ---------
__global__ __attribute__((amdgpu_waves_per_eu(4, 4))) __launch_bounds__(1024) void k_gru_fb(
    const float* __restrict__ Whh, const float* __restrict__ Gx,
    const float* __restrict__ Wih, const float* __restrict__ bhh_g,
    const float* __restrict__ Wf, const float* __restrict__ bf_g,
    const float* __restrict__ targets, const unsigned char* __restrict__ fmask,
    const int* __restrict__ flag, float* __restrict__ out)
{
    __shared__ __align__(16) float hq[8 * 268];
    __shared__ float gsum[768];
    __shared__ float tfl[16];
    __shared__ float wtfL[30 * 256];
    __shared__ float WfL[2560];
    const int b = blockIdx.x, tid = threadIdx.x;
    const int kgs = tid & 15, rg = tid >> 4;
    const bool isGate = (tid < 256);
    float bh0 = 0.f, bh1 = 0.f, bh2 = 0.f, hold = 0.f;
    if (isGate) { bh0 = bhh_g[tid]; bh1 = bhh_g[tid + 256]; bh2 = bhh_g[tid + 512]; }
    const bool isProj = (tid >= 256 && tid < 416);
    const int oc = (tid - 256) >> 4, seg = tid & 15;
    float bfc = isProj ? bf_g[oc] : 0.f;
    const bool isWr = isProj && (seg == 15);
    const int int32mode = flag[0];
    for (int e = tid; e < 7680; e += 1024) {
        int cp = e >> 8, jj = e & 255;
        int g = cp / 10, c = cp - g * 10;
        wtfL[e] = Wih[(g * 256 + jj) * 138 + 128 + c];
    }
    for (int e = tid; e < 2560; e += 1024) WfL[e] = Wf[e];
    for (int e = tid; e < 8 * 268; e += 1024) hq[e] = 0.f;
    if (tid < 16) tfl[tid] = 0.f;
    __syncthreads();
    const float4* hbase = (const float4*)&hq[(kgs >> 1) * 268 + kgs * 16];
    const float4* wbase = ((const float4*)Whh) + kgs * 4;
    int tr = 0;
    for (int t = 0; t < 1024; t++) {
        float gxr = 0.f, gxz = 0.f, gxn = 0.f;
        if (isGate) {
            const float* gx = &Gx[((long)t * 32 + b) * 768];
            gxr = gx[tid]; gxz = gx[tid + 256]; gxn = gx[tid + 512];
        }
        float tgt = 0.f; int fmv = 0;
        if (isWr) {
            tgt = targets[((long)b * 1024 + t) * 10 + oc];
            fmv = int32mode ? ((const int*)fmask)[t * 32 + b] : (int)fmask[t * 32 + b];
        }
        float4 hv[4];
#pragma unroll
        for (int q = 0; q < 4; q++) hv[q] = hbase[q];
        float4 sb[3][4];
#pragma unroll
        for (int pq = 0; pq < 3; pq++) {
            int ro = tr + pq; if (ro >= 12) ro -= 12;
            const float4* wp = wbase + (rg * 12 + ro) * 64;
#pragma unroll
            for (int q = 0; q < 4; q++) sb[pq][q] = wp[q];
        }
#pragma unroll
        for (int i = 0; i < 12; i++) {
            const int sl = i % 3;
            int ro = tr + i; if (ro >= 12) ro -= 12;
            float s = 0.f;
#pragma unroll
            for (int q = 0; q < 4; q++) {
                s = fmaf(sb[sl][q].x, hv[q].x, s);
                s = fmaf(sb[sl][q].y, hv[q].y, s);
                s = fmaf(sb[sl][q].z, hv[q].z, s);
                s = fmaf(sb[sl][q].w, hv[q].w, s);
            }
            if (i + 3 < 12) {
                int rn = tr + i + 3; if (rn >= 12) rn -= 12;
                const float4* wp = wbase + (rg * 12 + rn) * 64;
#pragma unroll
                for (int q = 0; q < 4; q++) sb[sl][q] = wp[q];
            }
            s = dpp_add<0x111>(s);
            s = dpp_add<0x112>(s);
            s = dpp_add<0x114>(s);
            s = dpp_add<0x118>(s);
            if (kgs == 15) gsum[rg * 12 + ro] = s;
        }
        __syncthreads();
        if (isGate) {
            float gr = gxr, gz = gxz, gn = gxn;
#pragma unroll
            for (int c = 0; c < 10; c++) {
                float tv = tfl[c];
                gr = fmaf(tv, wtfL[c * 256 + tid], gr);
                gz = fmaf(tv, wtfL[(10 + c) * 256 + tid], gz);
                gn = fmaf(tv, wtfL[(20 + c) * 256 + tid], gn);
            }
            float ar = gsum[tid] + bh0;
            float az = gsum[tid + 256] + bh1;
            float an = gsum[tid + 512] + bh2;
            float r = 1.0f / (1.0f + expf(-(gr + ar)));
            float z = 1.0f / (1.0f + expf(-(gz + az)));
            float n = tanhf(fmaf(r, an, gn));
            float hnew = (1.0f - z) * n + z * hold;
            hold = hnew;
#pragma unroll
            for (int c = 0; c < 8; c++) hq[c * 268 + tid] = hnew;
        }
        __syncthreads();
        if (isProj) {
            const float* hp2 = &hq[(seg >> 1) * 268 + seg * 16];
            const float* wfp = &WfL[oc * 256 + seg * 16];
            float s = 0.f;
#pragma unroll
            for (int i = 0; i < 16; i++) s = fmaf(wfp[i], hp2[i], s);
            s = dpp_add<0x111>(s);
            s = dpp_add<0x112>(s);
            s = dpp_add<0x114>(s);
            s = dpp_add<0x118>(s);
            if (isWr) {
                float o = s + bfc;
                out[((long)b * 1024 + t) * 10 + oc] = o;
                float pred = (o > 0.f) ? 1.f : 0.f;
                tfl[oc] = fmv ? tgt : pred;
            }
        }
        tr++; if (tr == 12) tr = 0;
    }
}

extern "C" void kernel_launch(void* const* d_in, const int* in_sizes, int n_in,
                              void* d_out, int out_size, void* d_ws, size_t ws_size,
                              hipStream_t stream) {
    (void)in_sizes; (void)n_in; (void)out_size; (void)ws_size;
    const float* features = (const float*)d_in[0];
    const float* targets  = (const float*)d_in[1];
    const unsigned char* fmask = (const unsigned char*)d_in[2];
    const float* W1  = (const float*)d_in[3];
    const float* b1  = (const float*)d_in[4];
    const float* g1  = (const float*)d_in[5];
    const float* be1 = (const float*)d_in[6];
    const float* m1  = (const float*)d_in[7];
    const float* v1  = (const float*)d_in[8];
    const float* W2  = (const float*)d_in[9];
    const float* b2  = (const float*)d_in[10];
    const float* g2  = (const float*)d_in[11];
    const float* be2 = (const float*)d_in[12];
    const float* m2  = (const float*)d_in[13];
    const float* v2  = (const float*)d_in[14];
    const float* W3  = (const float*)d_in[15];
    const float* b3  = (const float*)d_in[16];
    const float* g3  = (const float*)d_in[17];
    const float* be3 = (const float*)d_in[18];
    const float* m3  = (const float*)d_in[19];
    const float* v3  = (const float*)d_in[20];
    const float* Wih = (const float*)d_in[21];
    const float* Whh = (const float*)d_in[22];
    const float* bih = (const float*)d_in[23];
    const float* bhh = (const float*)d_in[24];
    const float* Wf  = (const float*)d_in[25];
    const float* bf  = (const float*)d_in[26];

    char* w = (char*)d_ws;
    _Float16* WhhH = (_Float16*)(w + 0);                // 393216 B (in 786432 slot)
    float* WxT = (float*)(w + 786432);                  // 393216 B
    float* W2T = (float*)(w + 1179648);                 // 1638400 B
    float* W3T = (float*)(w + 2818048);                 // 1638400 B
    int*   flag = (int*)(w + 4456448);                  // 512 B slot
    float* X1  = (float*)(w + 4456960);                 // 128 MB; reused as Gx after conv2
    float* Gx  = X1;
    float* X2  = (float*)(w + 4456960 + 134217728);     // 32 MB
    float* F   = (float*)(w + 4456960 + 134217728 + 33554432); // 16 MB
    float* out = (float*)d_out;

    const int GRU_LDS = 147456 + (256 + 768 + 16) * 4;  // 151616 B
    hipError_t rc = hipFuncSetAttribute((const void*)k_gru,
        hipFuncAttributeMaxDynamicSharedMemorySize, GRU_LDS);

    k_prep<<<1600, 256, 0, stream>>>(Wih, Whh, W2, W3, fmask, WhhH, WxT, W2T, W3T, flag);
    k_conv1<<<8192, 256, 0, stream>>>(features, W1, b1, g1, be1, m1, v1, X1);
    k_conv2<<<1024, 256, 0, stream>>>(X1, W2T, b2, g2, be2, m2, v2, X2);
    k_conv3<<<4096, 256, 0, stream>>>(X2, W3T, b3, g3, be3, m3, v3, F);
    k_gemm<<<1536, 256, 0, stream>>>(F, WxT, bih, Gx);
    if (rc == hipSuccess) {
        k_gru<<<32, 1024, GRU_LDS, stream>>>(WhhH, Gx, Wih, bhh, Wf, bf,
                                             targets, fmask, flag, out);
    } else {
        k_gru_fb<<<32, 1024, 0, stream>>>(Whh, Gx, Wih, bhh, Wf, bf,
                                          targets, fmask, flag, out);
    }
}

// Round 18
// 9316.925 us; speedup vs baseline: 2.1124x; 2.1124x over previous
//
#include <hip/hip_runtime.h>
#include <math.h>

#define EPSF 1e-5f

typedef __attribute__((ext_vector_type(2))) float f2;
typedef __attribute__((ext_vector_type(4))) float f4;
typedef __attribute__((ext_vector_type(8))) _Float16 h8;

// packed fp32 FMA with x broadcast via op_sel (lo or hi half of the x pair)
#define PK_FMA_LO(ACC, W, X) \
    asm("v_pk_fma_f32 %0, %1, %2, %0 op_sel:[0,0,0] op_sel_hi:[1,0,1]" \
        : "+v"(ACC) : "v"(W), "v"(X))
#define PK_FMA_HI(ACC, W, X) \
    asm("v_pk_fma_f32 %0, %1, %2, %0 op_sel:[0,1,0] op_sel_hi:[1,1,1]" \
        : "+v"(ACC) : "v"(W), "v"(X))

// DPP helper: v += value from lane (i - N) within the 16-lane DPP row (0 if OOB)
template<int CTRL>
__device__ __forceinline__ float dpp_add(float v) {
    int s = __builtin_amdgcn_update_dpp(0, __float_as_int(v), CTRL, 0xf, 0xf, true);
    return v + __int_as_float(s);
}

// async global->LDS, 16B per lane; LDS dest = wave-uniform base + lane*16
__device__ __forceinline__ void gl_lds16(const void* g, void* l) {
    __builtin_amdgcn_global_load_lds(
        (const __attribute__((address_space(1))) void*)g,
        (__attribute__((address_space(3))) void*)l, 16, 0, 0);
}

// ---------------- prep: weight transposes + bool-dtype detect ----------------
__global__ __launch_bounds__(256) void k_prep(
    const float* __restrict__ Wih, const float* __restrict__ Whh,
    const float* __restrict__ W2, const float* __restrict__ W3,
    const unsigned char* __restrict__ fmask,
    _Float16* __restrict__ WhhH, float* __restrict__ WxT,
    float* __restrict__ W2T, float* __restrict__ W3T, int* __restrict__ flag)
{
    int idx = blockIdx.x * 256 + threadIdx.x;
    if (idx < 196608) {                 // Whh[768][256] -> WhhH[k/8][j][8] fp16
        int j = idx >> 8, k = idx & 255;
        WhhH[(k >> 3) * 6144 + j * 8 + (k & 7)] = (_Float16)Whh[idx];
    }
    if (idx < 105984) {                 // Wih[768][138] x-part -> WxT[128][768]
        int j = idx / 138, k = idx % 138;
        if (k < 128) WxT[k * 768 + j] = Wih[idx];
    }
    if (idx < 409600) {                 // W[co][ci][5][5] -> WT[tap][ci][co]
        int co = idx / 3200, r = idx % 3200;
        int ci = r / 25, tap = r % 25;
        int dst = (tap * 128 + ci) * 128 + co;
        W2T[dst] = W2[idx];
        W3T[dst] = W3[idx];
    }
    if (idx == 0) {                     // bool stored as int32? bytes 1,2,3 of each word all zero
        int nz = 0;
        for (int i = 0; i < 4096; i++) if ((i & 3) != 0) nz |= fmask[i];
        *flag = nz ? 0 : 1;
    }
}

// ---------------- conv1: [32,1,1024,40] -> X1[b][t][m1(8)][co(128)] ----------------
__global__ __launch_bounds__(256) void k_conv1(
    const float* __restrict__ X, const float* __restrict__ W1,
    const float* __restrict__ bb, const float* __restrict__ gg,
    const float* __restrict__ be, const float* __restrict__ mm_,
    const float* __restrict__ vv, float* __restrict__ X1)
{
    __shared__ __align__(16) float xs[8][44];
    __shared__ __align__(16) float ws[25][128];
    __shared__ float sc[128], sh[128];
    int bid = blockIdx.x;
    int b = bid >> 8, t0 = (bid & 255) << 2;
    int tid = threadIdx.x;
    for (int e = tid; e < 8 * 44; e += 256) {
        int tt = e / 44, mm = e % 44;
        int gt = t0 + tt - 2, gm = mm - 2;
        float val = 0.f;
        if (gt >= 0 && gt < 1024 && gm >= 0 && gm < 40)
            val = X[(b * 1024 + gt) * 40 + gm];
        xs[tt][mm] = val;
    }
    for (int e = tid; e < 3200; e += 256) {
        int tap = e >> 7, co = e & 127;
        ws[tap][co] = W1[co * 25 + tap];
    }
    if (tid < 128) {
        float s = gg[tid] / sqrtf(vv[tid] + EPSF);
        sc[tid] = s;
        sh[tid] = (bb[tid] - mm_[tid]) * s + be[tid];
    }
    __syncthreads();
    int cog = tid >> 5;          // 8 groups x 16 co
    int m1i = (tid >> 2) & 7;    // pooled mel
    int tp  = tid & 3;           // t'
    int co0 = cog * 16;
    float val[5][16];
#pragma unroll
    for (int p = 0; p < 5; p++)
#pragma unroll
        for (int i = 0; i < 16; i++) val[p][i] = 0.f;
#pragma unroll
    for (int dt = 0; dt < 5; dt++) {
#pragma unroll
        for (int dm = 0; dm < 5; dm++) {
            float w[16];
#pragma unroll
            for (int i = 0; i < 16; i += 4)
                *(float4*)&w[i] = *(const float4*)&ws[dt * 5 + dm][co0 + i];
#pragma unroll
            for (int p = 0; p < 5; p++) {
                float x = xs[tp + dt][m1i * 5 + p + dm];
#pragma unroll
                for (int i = 0; i < 16; i++) val[p][i] = fmaf(x, w[i], val[p][i]);
            }
        }
    }
    float outv[16];
#pragma unroll
    for (int i = 0; i < 16; i++) {
        float s = sc[co0 + i], h = sh[co0 + i];
        float mx = 0.f;
#pragma unroll
        for (int p = 0; p < 5; p++) {
            float y = fmaf(val[p][i], s, h);
            y = fmaxf(y, 0.f);
            mx = fmaxf(mx, y);
        }
        outv[i] = mx;
    }
    float* dst = &X1[(((long)(b * 1024 + t0 + tp)) * 8 + m1i) * 128 + co0];
#pragma unroll
    for (int i = 0; i < 16; i += 4) *(float4*)&dst[i] = *(float4*)&outv[i];
}

// -------- conv2 v4: pk_fma + 2 t-rows/thread (w-reads amortized 2x) --------
__global__ __attribute__((amdgpu_waves_per_eu(2, 2))) __launch_bounds__(256) void k_conv2(
    const float* __restrict__ X1, const float* __restrict__ W2T,
    const float* __restrict__ bb, const float* __restrict__ gg,
    const float* __restrict__ be, const float* __restrict__ mm_,
    const float* __restrict__ vv, float* __restrict__ X2)
{
    __shared__ __align__(16) float xs[36 * 196];     // [tt][ci*12 + m]
    __shared__ __align__(16) float ws[5 * 16 * 132]; // [dm][ci][co(128, pad 132)]
    __shared__ float sc[128], sh[128];
    int bid = blockIdx.x;
    int t0 = (bid & 31) << 5, b = bid >> 5;
    int tid = threadIdx.x;
    int tp = tid & 15, cog = tid >> 4;
    if (tid < 128) {
        float s = gg[tid] / sqrtf(vv[tid] + EPSF);
        sc[tid] = s;
        sh[tid] = (bb[tid] - mm_[tid]) * s + be[tid];
    }
    f2 accp[2][4][8];                    // [t-half][co pair][m]
#pragma unroll
    for (int th = 0; th < 2; th++)
#pragma unroll
        for (int p = 0; p < 4; p++)
#pragma unroll
            for (int m = 0; m < 8; m++) accp[th][p][m] = (f2){0.f, 0.f};

    for (int cc = 0; cc < 8; cc++) {
        __syncthreads();
        for (int e = tid; e < 1728; e += 256) {
            int ci = e & 15, r = e >> 4;          // r 0..107
            int tt = r / 3, mg = r - tt * 3;
            int gt = t0 + tt - 2;
            float4 v = {0.f, 0.f, 0.f, 0.f};
            if (gt >= 0 && gt < 1024) {
                const float* src = &X1[(((long)(b * 1024 + gt)) * 8) * 128 + cc * 16 + ci];
                float* pv = (float*)&v;
#pragma unroll
                for (int k2 = 0; k2 < 4; k2++) {
                    int gm = mg * 4 + k2 - 2;
                    if (gm >= 0 && gm < 8) pv[k2] = src[gm * 128];
                }
            }
            *(float4*)&xs[tt * 196 + ci * 12 + mg * 4] = v;
        }
        for (int dt = 0; dt < 5; dt++) {
            __syncthreads();
            for (int e = tid; e < 10240; e += 256) {
                int co = e & 127, ci = (e >> 7) & 15, dm = e >> 11;
                ws[dm * 2112 + ci * 132 + co] =
                    W2T[((dt * 5 + dm) * 128 + cc * 16 + ci) * 128 + co];
            }
            __syncthreads();
            for (int ci = 0; ci < 16; ci++) {
                f2 x2[2][6];
#pragma unroll
                for (int th = 0; th < 2; th++) {
                    const float* xp = &xs[(tp + th * 16 + dt) * 196 + ci * 12];
                    f4 a = *(const f4*)&xp[0];
                    f4 bv = *(const f4*)&xp[4];
                    f4 cv = *(const f4*)&xp[8];
                    x2[th][0] = (f2){a.x, a.y};   x2[th][1] = (f2){a.z, a.w};
                    x2[th][2] = (f2){bv.x, bv.y}; x2[th][3] = (f2){bv.z, bv.w};
                    x2[th][4] = (f2){cv.x, cv.y}; x2[th][5] = (f2){cv.z, cv.w};
                }
                const float* wb = &ws[ci * 132];
#pragma unroll
                for (int dm = 0; dm < 5; dm++) {
                    const float* wr = wb + dm * 2112;
                    f4 wa = *(const f4*)&wr[cog * 4];
                    f4 wbv = *(const f4*)&wr[64 + cog * 4];
                    f2 wp[4];
                    wp[0] = (f2){wa.x, wa.y};   wp[1] = (f2){wa.z, wa.w};
                    wp[2] = (f2){wbv.x, wbv.y}; wp[3] = (f2){wbv.z, wbv.w};
#pragma unroll
                    for (int th = 0; th < 2; th++)
#pragma unroll
                        for (int m = 0; m < 8; m++) {
                            const int j = m + dm;
                            f2 xpair = x2[th][j >> 1];
                            if (j & 1) {
                                PK_FMA_HI(accp[th][0][m], wp[0], xpair);
                                PK_FMA_HI(accp[th][1][m], wp[1], xpair);
                                PK_FMA_HI(accp[th][2][m], wp[2], xpair);
                                PK_FMA_HI(accp[th][3][m], wp[3], xpair);
                            } else {
                                PK_FMA_LO(accp[th][0][m], wp[0], xpair);
                                PK_FMA_LO(accp[th][1][m], wp[1], xpair);
                                PK_FMA_LO(accp[th][2][m], wp[2], xpair);
                                PK_FMA_LO(accp[th][3][m], wp[3], xpair);
                            }
                        }
                }
            }
        }
    }
#pragma unroll
    for (int th = 0; th < 2; th++) {
        int t = t0 + th * 16 + tp;
#pragma unroll
        for (int g = 0; g < 2; g++) {
            int cobase = g * 64 + cog * 4;
#pragma unroll
            for (int m2 = 0; m2 < 2; m2++) {
                float4 ov;
                float* po = (float*)&ov;
#pragma unroll
                for (int c = 0; c < 4; c++) {
                    float s = sc[cobase + c], h = sh[cobase + c];
                    float mx = 0.f;
#pragma unroll
                    for (int q = 0; q < 4; q++) {
                        f2 av = accp[th][g * 2 + (c >> 1)][m2 * 4 + q];
                        float a = (c & 1) ? av.y : av.x;
                        float y = fmaf(a, s, h);
                        y = fmaxf(y, 0.f);
                        mx = fmaxf(mx, y);
                    }
                    po[c] = mx;
                }
                *(float4*)&X2[(((long)(b * 1024 + t)) * 2 + m2) * 128 + cobase] = ov;
            }
        }
    }
}

// ------- conv3 (tap-pruned, conflict-free; validated R9: conflicts 6.5e8 -> 0) -------
__global__ __launch_bounds__(256) void k_conv3(
    const float* __restrict__ X2, const float* __restrict__ W3T,
    const float* __restrict__ bb, const float* __restrict__ gg,
    const float* __restrict__ be, const float* __restrict__ mm_,
    const float* __restrict__ vv, float* __restrict__ F)
{
    __shared__ __align__(16) float xs[20 * 66];     // [t''][ci*2+m], stride 66
    __shared__ __align__(16) float ws[3][32][64];   // [dm-1][ci][co]
    __shared__ float sc[64], sh[64];
    int bid = blockIdx.x;
    int coh = bid & 1, t0 = ((bid >> 1) & 63) << 4, b = bid >> 7;
    int co_base = coh * 64;
    int tid = threadIdx.x;
    int tp = tid & 15, cog = tid >> 4;
    if (tid < 64) {
        int co = co_base + tid;
        float s = gg[co] / sqrtf(vv[co] + EPSF);
        sc[tid] = s;
        sh[tid] = (bb[co] - mm_[co]) * s + be[co];
    }
    float acc[4][2];
#pragma unroll
    for (int c = 0; c < 4; c++) { acc[c][0] = 0.f; acc[c][1] = 0.f; }

    for (int cc = 0; cc < 4; cc++) {
        __syncthreads();
        for (int e = tid; e < 20 * 64; e += 256) {
            int tt = e >> 6, r = e & 63;
            int ci = r >> 1, m = r & 1;
            int gt = t0 + tt - 2;
            float v = 0.f;
            if (gt >= 0 && gt < 1024)
                v = X2[(((long)(b * 1024 + gt)) * 2 + m) * 128 + cc * 32 + ci];
            xs[tt * 66 + ci * 2 + m] = v;
        }
        for (int dt = 0; dt < 5; dt++) {
            __syncthreads();
            for (int e = tid; e < 3 * 32 * 64; e += 256) {
                int co = e & 63, ci = (e >> 6) & 31, dmi = e >> 11;
                ws[dmi][ci][co] = W3T[((dt * 5 + dmi + 1) * 128 + cc * 32 + ci) * 128 + co_base + co];
            }
            __syncthreads();
            for (int ci = 0; ci < 32; ci++) {
                float2 x = *(const float2*)&xs[(tp + dt) * 66 + ci * 2];
                float w1[4], w2[4], w3[4];
                *(float4*)w1 = *(const float4*)&ws[0][ci][cog * 4];
                *(float4*)w2 = *(const float4*)&ws[1][ci][cog * 4];
                *(float4*)w3 = *(const float4*)&ws[2][ci][cog * 4];
#pragma unroll
                for (int c = 0; c < 4; c++) acc[c][0] = fmaf(w2[c], x.x, acc[c][0]);
#pragma unroll
                for (int c = 0; c < 4; c++) acc[c][0] = fmaf(w3[c], x.y, acc[c][0]);
#pragma unroll
                for (int c = 0; c < 4; c++) acc[c][1] = fmaf(w1[c], x.x, acc[c][1]);
#pragma unroll
                for (int c = 0; c < 4; c++) acc[c][1] = fmaf(w2[c], x.y, acc[c][1]);
            }
        }
    }
    float4 ov;
    float* po = (float*)&ov;
#pragma unroll
    for (int c = 0; c < 4; c++) {
        float s = sc[cog * 4 + c], h = sh[cog * 4 + c];
        float y0 = fmaxf(fmaf(acc[c][0], s, h), 0.f);
        float y1 = fmaxf(fmaf(acc[c][1], s, h), 0.f);
        po[c] = fmaxf(y0, y1);
    }
    *(float4*)&F[((long)(t0 + tp) * 32 + b) * 128 + co_base + cog * 4] = ov;
}

// ---------------- Gx = F @ Wihx.T + bih : [32768,128]x[128,768] ----------------
__global__ __launch_bounds__(256) void k_gemm(
    const float* __restrict__ F, const float* __restrict__ WxT,
    const float* __restrict__ bih, float* __restrict__ Gx)
{
    __shared__ __align__(16) float Fs[64][33];
    __shared__ __align__(16) float Ws[32][256];
    int bid = blockIdx.x;
    int jt = bid % 3, tb0 = (bid / 3) * 64;
    int tid = threadIdx.x;
    int tx = tid & 31, ty = tid >> 5;
    float acc[8][8];
#pragma unroll
    for (int i = 0; i < 8; i++)
#pragma unroll
        for (int j = 0; j < 8; j++) acc[i][j] = 0.f;
    for (int cc = 0; cc < 4; cc++) {
        __syncthreads();
        for (int e = tid; e < 64 * 32; e += 256) {
            int ci = e & 31, i = e >> 5;
            Fs[i][ci] = F[(long)(tb0 + i) * 128 + cc * 32 + ci];
        }
        for (int e = tid; e < 32 * 256; e += 256) {
            int jj = e & 255, ci = e >> 8;
            Ws[ci][jj] = WxT[(cc * 32 + ci) * 768 + jt * 256 + jj];
        }
        __syncthreads();
        for (int ci = 0; ci < 32; ci++) {
            float a[8], w[8];
#pragma unroll
            for (int i = 0; i < 8; i++) a[i] = Fs[ty * 8 + i][ci];
            *(float4*)&w[0] = *(const float4*)&Ws[ci][tx * 8];
            *(float4*)&w[4] = *(const float4*)&Ws[ci][tx * 8 + 4];
#pragma unroll
            for (int i = 0; i < 8; i++)
#pragma unroll
                for (int j = 0; j < 8; j++) acc[i][j] = fmaf(a[i], w[j], acc[i][j]);
        }
    }
    float bj[8];
#pragma unroll
    for (int j = 0; j < 8; j++) bj[j] = bih[jt * 256 + tx * 8 + j];
#pragma unroll
    for (int i = 0; i < 8; i++) {
        float o[8];
#pragma unroll
        for (int j = 0; j < 8; j++) o[j] = acc[i][j] + bj[j];
        float* dst = &Gx[(long)(tb0 + ty * 8 + i) * 768 + jt * 256 + tx * 8];
        *(float4*)&dst[0] = *(float4*)&o[0];
        *(float4*)&dst[4] = *(float4*)&o[4];
    }
}

// ====== GRU ring v4 (validated R12/R14/R16): fp16 weights, fp32 h ======
// 4.87 ms, absmax 0.00390625, ~97% of its LDS-pipe floor. R17's hybrid
// register-residency attempt spilled (5th allocator refusal) -- this DMA-ring
// structure is the practical optimum reachable from HIP source.
__global__ __attribute__((amdgpu_waves_per_eu(4, 4))) __launch_bounds__(1024) void k_gru(
    const _Float16* __restrict__ WhhH, const float* __restrict__ Gx,
    const float* __restrict__ Wih, const float* __restrict__ bhh_g,
    const float* __restrict__ Wf, const float* __restrict__ bf_g,
    const float* __restrict__ targets, const unsigned char* __restrict__ fmask,
    const int* __restrict__ flag, float* __restrict__ out)
{
    extern __shared__ float lds[];
    char* bufb  = (char*)lds;       // 3 slots * 49152 B = 147456 B
    float* hq   = lds + 36864;      // 256
    float* gsum = hq + 256;         // 768
    float* tfl  = gsum + 768;       // 16
    const int b = blockIdx.x, tid = threadIdx.x;
    const int lane = tid & 63, wvi = tid >> 6;
    const bool isCons = (wvi < 12);
    const bool isGate = (tid < 256);
    const bool isProj = (tid >= 256 && tid < 416);
    const bool isProd = (wvi >= 12);

    float wtf0[10], wtf1[10], wtf2[10];
    float bh0 = 0.f, bh1 = 0.f, bh2 = 0.f, hold = 0.f;
    if (isGate) {
#pragma unroll
        for (int c = 0; c < 10; c++) {
            wtf0[c] = Wih[tid * 138 + 128 + c];
            wtf1[c] = Wih[(tid + 256) * 138 + 128 + c];
            wtf2[c] = Wih[(tid + 512) * 138 + 128 + c];
        }
        bh0 = bhh_g[tid]; bh1 = bhh_g[tid + 256]; bh2 = bhh_g[tid + 512];
    }
    const int oc = (tid - 256) >> 4, seg = tid & 15;
    float wf16[16];
    float bfc = 0.f;
    int int32mode = 0;
    if (isProj) {
#pragma unroll
        for (int i = 0; i < 16; i++) wf16[i] = Wf[oc * 256 + seg * 16 + i];
        bfc = bf_g[oc];
        int32mode = flag[0];
    }
    const bool isWr = isProj && (seg == 15);

    if (tid < 256) hq[tid] = 0.f;
    if (tid < 16) tfl[tid] = 0.f;
    __syncthreads();   // no gl_lds outstanding yet: safe

    const int wv = wvi - 12;          // producer wave 0..3
    const char* WhhB = (const char*)WhhH;
    // prologue: stage chunks 0 (slot 0) and 1 (slot 1); chunk g = bytes [g*49152, +49152)
    if (isProd) {
        for (int g = 0; g < 2; g++) {
#pragma unroll
            for (int i = 0; i < 12; i++) {
                int off = (wv * 12 + i) * 1024;
                gl_lds16(WhhB + g * 49152 + off + lane * 16, bufb + g * 49152 + off);
            }
        }
        asm volatile("s_waitcnt vmcnt(12)");   // chunk 0 arrived
    }
    asm volatile("s_barrier" ::: "memory");

    const f4* fh = (const f4*)hq;
    int slotc = 0, slotp = 2;

    for (int t = 0; t < 1024; t++) {
        float gxr = 0.f, gxz = 0.f, gxn = 0.f;
        if (isGate) {
            const float* gx = &Gx[((long)t * 32 + b) * 768];
            gxr = gx[tid]; gxz = gx[tid + 256]; gxn = gx[tid + 512];
        }
        float tgt = 0.f; int fmv = 0;
        if (isWr) {
            tgt = targets[((long)b * 1024 + t) * 10 + oc];
            fmv = int32mode ? ((const int*)fmask)[t * 32 + b] : (int)fmask[t * 32 + b];
        }
        float acc = 0.f;

        for (int c = 0; c < 8; c++) {
            if (isProd) {
                int rs = (c + 2) & 7;                      // chunk being staged
                const char* srcb = WhhB + rs * 49152;
                char* dstb = bufb + slotp * 49152;
#pragma unroll
                for (int i = 0; i < 12; i++) {
                    int off = (wv * 12 + i) * 1024;
                    gl_lds16(srcb + off + lane * 16, dstb + off);
                }
                asm volatile("s_waitcnt vmcnt(12)");       // chunk c+1 arrived
            } else if (isCons) {
                const h8* wp = (const h8*)(bufb + slotc * 49152);
#pragma unroll
                for (int g = 0; g < 4; g++) {
                    h8 w = wp[g * 768 + tid];
                    f4 ha = fh[c * 8 + g * 2], hb = fh[c * 8 + g * 2 + 1];
                    acc = fmaf((float)w[0], ha.x, acc);
                    acc = fmaf((float)w[1], ha.y, acc);
                    acc = fmaf((float)w[2], ha.z, acc);
                    acc = fmaf((float)w[3], ha.w, acc);
                    acc = fmaf((float)w[4], hb.x, acc);
                    acc = fmaf((float)w[5], hb.y, acc);
                    acc = fmaf((float)w[6], hb.z, acc);
                    acc = fmaf((float)w[7], hb.w, acc);
                }
            }
            slotc++; if (slotc == 3) slotc = 0;
            slotp++; if (slotp == 3) slotp = 0;
            asm volatile("s_barrier" ::: "memory");
        }

        if (isCons) gsum[tid] = acc;
        asm volatile("s_barrier" ::: "memory");   // B1: gsum ready

        if (isGate) {
            float gr = gxr, gz = gxz, gn = gxn;
#pragma unroll
            for (int c = 0; c < 10; c++) {
                float tv = tfl[c];
                gr = fmaf(tv, wtf0[c], gr);
                gz = fmaf(tv, wtf1[c], gz);
                gn = fmaf(tv, wtf2[c], gn);
            }
            float ar = gsum[tid] + bh0;
            float az = gsum[tid + 256] + bh1;
            float an = gsum[tid + 512] + bh2;
            float r = 1.0f / (1.0f + expf(-(gr + ar)));
            float z = 1.0f / (1.0f + expf(-(gz + az)));
            float n = tanhf(fmaf(r, an, gn));
            float hnew = (1.0f - z) * n + z * hold;
            hold = hnew;
            hq[tid] = hnew;
        }
        asm volatile("s_barrier" ::: "memory");   // B2: h ready

        if (isProj) {
            const float* hp = &hq[seg * 16];
            float s = 0.f;
#pragma unroll
            for (int i = 0; i < 16; i++) s = fmaf(wf16[i], hp[i], s);
            s = dpp_add<0x111>(s);
            s = dpp_add<0x112>(s);
            s = dpp_add<0x114>(s);
            s = dpp_add<0x118>(s);   // lane seg==15 holds full sum
            if (isWr) {
                float o = s + bfc;
                out[((long)b * 1024 + t) * 10 + oc] = o;
                float pred = (o > 0.f) ? 1.f : 0.f;
                tfl[oc] = fmv ? tgt : pred;
            }
        }
        // no extra barrier: hq/tfl consumers separated by next step's chunk
        // barriers + B1 before first use.
    }
}

// ---------------- fallback GRU (R5): used only if dynamic LDS rejected ---------
__global__ __attribute__((amdgpu_waves_per_eu(4, 4))) __launch_bounds__(1024) void k_gru_fb(
    const float* __restrict__ Whh, const float* __restrict__ Gx,
    const float* __restrict__ Wih, const float* __restrict__ bhh_g,
    const float* __restrict__ Wf, const float* __restrict__ bf_g,
    const float* __restrict__ targets, const unsigned char* __restrict__ fmask,
    const int* __restrict__ flag, float* __restrict__ out)
{
    __shared__ __align__(16) float hq[8 * 268];
    __shared__ float gsum[768];
    __shared__ float tfl[16];
    __shared__ float wtfL[30 * 256];
    __shared__ float WfL[2560];
    const int b = blockIdx.x, tid = threadIdx.x;
    const int kgs = tid & 15, rg = tid >> 4;
    const bool isGate = (tid < 256);
    float bh0 = 0.f, bh1 = 0.f, bh2 = 0.f, hold = 0.f;
    if (isGate) { bh0 = bhh_g[tid]; bh1 = bhh_g[tid + 256]; bh2 = bhh_g[tid + 512]; }
    const bool isProj = (tid >= 256 && tid < 416);
    const int oc = (tid - 256) >> 4, seg = tid & 15;
    float bfc = isProj ? bf_g[oc] : 0.f;
    const bool isWr = isProj && (seg == 15);
    const int int32mode = flag[0];
    for (int e = tid; e < 7680; e += 1024) {
        int cp = e >> 8, jj = e & 255;
        int g = cp / 10, c = cp - g * 10;
        wtfL[e] = Wih[(g * 256 + jj) * 138 + 128 + c];
    }
    for (int e = tid; e < 2560; e += 1024) WfL[e] = Wf[e];
    for (int e = tid; e < 8 * 268; e += 1024) hq[e] = 0.f;
    if (tid < 16) tfl[tid] = 0.f;
    __syncthreads();
    const float4* hbase = (const float4*)&hq[(kgs >> 1) * 268 + kgs * 16];
    const float4* wbase = ((const float4*)Whh) + kgs * 4;
    int tr = 0;
    for (int t = 0; t < 1024; t++) {
        float gxr = 0.f, gxz = 0.f, gxn = 0.f;
        if (isGate) {
            const float* gx = &Gx[((long)t * 32 + b) * 768];
            gxr = gx[tid]; gxz = gx[tid + 256]; gxn = gx[tid + 512];
        }
        float tgt = 0.f; int fmv = 0;
        if (isWr) {
            tgt = targets[((long)b * 1024 + t) * 10 + oc];
            fmv = int32mode ? ((const int*)fmask)[t * 32 + b] : (int)fmask[t * 32 + b];
        }
        float4 hv[4];
#pragma unroll
        for (int q = 0; q < 4; q++) hv[q] = hbase[q];
        float4 sb[3][4];
#pragma unroll
        for (int pq = 0; pq < 3; pq++) {
            int ro = tr + pq; if (ro >= 12) ro -= 12;
            const float4* wp = wbase + (rg * 12 + ro) * 64;
#pragma unroll
            for (int q = 0; q < 4; q++) sb[pq][q] = wp[q];
        }
#pragma unroll
        for (int i = 0; i < 12; i++) {
            const int sl = i % 3;
            int ro = tr + i; if (ro >= 12) ro -= 12;
            float s = 0.f;
#pragma unroll
            for (int q = 0; q < 4; q++) {
                s = fmaf(sb[sl][q].x, hv[q].x, s);
                s = fmaf(sb[sl][q].y, hv[q].y, s);
                s = fmaf(sb[sl][q].z, hv[q].z, s);
                s = fmaf(sb[sl][q].w, hv[q].w, s);
            }
            if (i + 3 < 12) {
                int rn = tr + i + 3; if (rn >= 12) rn -= 12;
                const float4* wp = wbase + (rg * 12 + rn) * 64;
#pragma unroll
                for (int q = 0; q < 4; q++) sb[sl][q] = wp[q];
            }
            s = dpp_add<0x111>(s);
            s = dpp_add<0x112>(s);
            s = dpp_add<0x114>(s);
            s = dpp_add<0x118>(s);
            if (kgs == 15) gsum[rg * 12 + ro] = s;
        }
        __syncthreads();
        if (isGate) {
            float gr = gxr, gz = gxz, gn = gxn;
#pragma unroll
            for (int c = 0; c < 10; c++) {
                float tv = tfl[c];
                gr = fmaf(tv, wtfL[c * 256 + tid], gr);
                gz = fmaf(tv, wtfL[(10 + c) * 256 + tid], gz);
                gn = fmaf(tv, wtfL[(20 + c) * 256 + tid], gn);
            }
            float ar = gsum[tid] + bh0;
            float az = gsum[tid + 256] + bh1;
            float an = gsum[tid + 512] + bh2;
            float r = 1.0f / (1.0f + expf(-(gr + ar)));
            float z = 1.0f / (1.0f + expf(-(gz + az)));
            float n = tanhf(fmaf(r, an, gn));
            float hnew = (1.0f - z) * n + z * hold;
            hold = hnew;
#pragma unroll
            for (int c = 0; c < 8; c++) hq[c * 268 + tid] = hnew;
        }
        __syncthreads();
        if (isProj) {
            const float* hp2 = &hq[(seg >> 1) * 268 + seg * 16];
            const float* wfp = &WfL[oc * 256 + seg * 16];
            float s = 0.f;
#pragma unroll
            for (int i = 0; i < 16; i++) s = fmaf(wfp[i], hp2[i], s);
            s = dpp_add<0x111>(s);
            s = dpp_add<0x112>(s);
            s = dpp_add<0x114>(s);
            s = dpp_add<0x118>(s);
            if (isWr) {
                float o = s + bfc;
                out[((long)b * 1024 + t) * 10 + oc] = o;
                float pred = (o > 0.f) ? 1.f : 0.f;
                tfl[oc] = fmv ? tgt : pred;
            }
        }
        tr++; if (tr == 12) tr = 0;
    }
}

extern "C" void kernel_launch(void* const* d_in, const int* in_sizes, int n_in,
                              void* d_out, int out_size, void* d_ws, size_t ws_size,
                              hipStream_t stream) {
    (void)in_sizes; (void)n_in; (void)out_size; (void)ws_size;
    const float* features = (const float*)d_in[0];
    const float* targets  = (const float*)d_in[1];
    const unsigned char* fmask = (const unsigned char*)d_in[2];
    const float* W1  = (const float*)d_in[3];
    const float* b1  = (const float*)d_in[4];
    const float* g1  = (const float*)d_in[5];
    const float* be1 = (const float*)d_in[6];
    const float* m1  = (const float*)d_in[7];
    const float* v1  = (const float*)d_in[8];
    const float* W2  = (const float*)d_in[9];
    const float* b2  = (const float*)d_in[10];
    const float* g2  = (const float*)d_in[11];
    const float* be2 = (const float*)d_in[12];
    const float* m2  = (const float*)d_in[13];
    const float* v2  = (const float*)d_in[14];
    const float* W3  = (const float*)d_in[15];
    const float* b3  = (const float*)d_in[16];
    const float* g3  = (const float*)d_in[17];
    const float* be3 = (const float*)d_in[18];
    const float* m3  = (const float*)d_in[19];
    const float* v3  = (const float*)d_in[20];
    const float* Wih = (const float*)d_in[21];
    const float* Whh = (const float*)d_in[22];
    const float* bih = (const float*)d_in[23];
    const float* bhh = (const float*)d_in[24];
    const float* Wf  = (const float*)d_in[25];
    const float* bf  = (const float*)d_in[26];

    char* w = (char*)d_ws;
    _Float16* WhhH = (_Float16*)(w + 0);                // 393216 B (in 786432 slot)
    float* WxT = (float*)(w + 786432);                  // 393216 B
    float* W2T = (float*)(w + 1179648);                 // 1638400 B
    float* W3T = (float*)(w + 2818048);                 // 1638400 B
    int*   flag = (int*)(w + 4456448);                  // 512 B slot
    float* X1  = (float*)(w + 4456960);                 // 128 MB; reused as Gx after conv2
    float* Gx  = X1;
    float* X2  = (float*)(w + 4456960 + 134217728);     // 32 MB
    float* F   = (float*)(w + 4456960 + 134217728 + 33554432); // 16 MB
    float* out = (float*)d_out;

    const int GRU_LDS = 147456 + (256 + 768 + 16) * 4;  // 151616 B
    hipError_t rc = hipFuncSetAttribute((const void*)k_gru,
        hipFuncAttributeMaxDynamicSharedMemorySize, GRU_LDS);

    k_prep<<<1600, 256, 0, stream>>>(Wih, Whh, W2, W3, fmask, WhhH, WxT, W2T, W3T, flag);
    k_conv1<<<8192, 256, 0, stream>>>(features, W1, b1, g1, be1, m1, v1, X1);
    k_conv2<<<1024, 256, 0, stream>>>(X1, W2T, b2, g2, be2, m2, v2, X2);
    k_conv3<<<4096, 256, 0, stream>>>(X2, W3T, b3, g3, be3, m3, v3, F);
    k_gemm<<<1536, 256, 0, stream>>>(F, WxT, bih, Gx);
    if (rc == hipSuccess) {
        k_gru<<<32, 1024, GRU_LDS, stream>>>(WhhH, Gx, Wih, bhh, Wf, bf,
                                             targets, fmask, flag, out);
    } else {
        k_gru_fb<<<32, 1024, 0, stream>>>(Whh, Gx, Wih, bhh, Wf, bf,
                                          targets, fmask, flag, out);
    }
}